// Round 6
// baseline (465.800 us; speedup 1.0000x reference)
//
#include <hip/hip_runtime.h>
#include <stdint.h>

#define N_NODES 100000
#define N_EDGES 1600000
#define IN_DIM 256
#define HID_DIM 128
#define OUT_DIM 128

#define NBUCK 391        // ceil(100000/256) buckets of 256 nodes
#define CHUNK 2048       // edges per block in bucket passes (782 blocks -> 3/CU)

typedef __attribute__((ext_vector_type(8))) short short8;
typedef __attribute__((ext_vector_type(4))) float floatx4;

__device__ __forceinline__ float bf2f(unsigned short u) {
    union { unsigned int i; float f; } v; v.i = ((unsigned int)u) << 16; return v.f;
}
__device__ __forceinline__ unsigned short f2bf(float f) {
    union { float fl; unsigned int i; } v; v.fl = f;
    unsigned int x = v.i;
    return (unsigned short)((x + 0x7fffu + ((x >> 16) & 1u)) >> 16);
}
__device__ __forceinline__ float bflo(unsigned int u) {
    union { unsigned int i; float f; } v; v.i = u << 16; return v.f;
}
__device__ __forceinline__ float bfhi(unsigned int u) {
    union { unsigned int i; float f; } v; v.i = u & 0xffff0000u; return v.f;
}
__device__ __forceinline__ float asf(unsigned int u) {
    union { unsigned int i; float f; } v; v.i = u; return v.f;
}
__device__ __forceinline__ unsigned int asu(float f) {
    union { float fl; unsigned int i; } v; v.fl = f; return v.i;
}
// two f32 -> packed bf16x2 (RNE)
__device__ __forceinline__ unsigned int pack2(float a, float b) {
    unsigned int ua = asu(a), ub = asu(b);
    ua += 0x7fffu + ((ua >> 16) & 1u);
    ub += 0x7fffu + ((ub >> 16) & 1u);
    return (ua >> 16) | (ub & 0xffff0000u);
}
__device__ __forceinline__ short8 pack8(float4 a, float4 b) {
    union { unsigned int u[4]; short8 s; } r;
    r.u[0] = pack2(a.x, a.y);
    r.u[1] = pack2(a.z, a.w);
    r.u[2] = pack2(b.x, b.y);
    r.u[3] = pack2(b.z, b.w);
    return r.s;
}

// Runtime input-dtype probes: flags[0]=1 if floats are f32 (else bf16); flags[1]=1 if idx i64.
// Also zeroes bucket_cnt (folded k_zero).
__global__ void k_detect(const unsigned int* __restrict__ xu, const unsigned int* __restrict__ eu,
                         int* __restrict__ flags, int* __restrict__ bucket_cnt) {
    __shared__ int s_huge, s_odd;
    if (threadIdx.x == 0) { s_huge = 0; s_odd = 0; }
    if (threadIdx.x < NBUCK) bucket_cnt[threadIdx.x] = 0;
    __syncthreads();
    int huge = 0, odd = 0;
    for (int i = threadIdx.x; i < 1024; i += 512) {
        unsigned int b = xu[i];
        unsigned int e = (b >> 23) & 0xffu;
        if (e >= 0xf0u) huge = 1;
        if (eu[2 * i + 1] != 0) odd = 1;
    }
    if (huge) atomicOr(&s_huge, 1);
    if (odd) atomicOr(&s_odd, 1);
    __syncthreads();
    if (threadIdx.x == 0) { flags[0] = s_huge ? 0 : 1; flags[1] = s_odd ? 0 : 1; }
}

__device__ __forceinline__ int load_idx(const void* base, long long i, int i64m) {
    int v = i64m ? (int)((const long long*)base)[i] : ((const int*)base)[i];
    return v < 0 ? 0 : (v >= N_NODES ? N_NODES - 1 : v);
}
__device__ __forceinline__ float load_f(const void* base, long long i, int f32m) {
    return f32m ? ((const float*)base)[i] : bf2f(((const unsigned short*)base)[i]);
}

// ---- pass 1: bucket histogram; per-block hist saved for bscatter reuse ----
__global__ void k_bhist(const void* __restrict__ ei, const int* __restrict__ flags,
                        int* __restrict__ bucket_cnt, int* __restrict__ blockhist, int e) {
    __shared__ int h[NBUCK];
    for (int t = threadIdx.x; t < NBUCK; t += 256) h[t] = 0;
    __syncthreads();
    int i64m = flags[1];
    int base = blockIdx.x * CHUNK;
    int end = base + CHUNK < e ? base + CHUNK : e;
    for (int i = base + threadIdx.x; i < end; i += 256) {
        int d = load_idx(ei, (long long)N_EDGES + i, i64m);
        atomicAdd(&h[d >> 8], 1);
    }
    __syncthreads();
    int* bh = blockhist + (size_t)blockIdx.x * NBUCK;
    for (int t = threadIdx.x; t < NBUCK; t += 256) {
        int v = h[t];
        bh[t] = v;
        if (v) atomicAdd(&bucket_cnt[t], v);
    }
}

// ---- pass 2: scan bucket counts -> bases & cursors (1 block) ----
__global__ void k_bscan(const int* __restrict__ bucket_cnt, int* __restrict__ bucket_base,
                        int* __restrict__ bucket_cursor, int* __restrict__ rowptr) {
    __shared__ int lds[512];
    int t = threadIdx.x;
    int v = (t < NBUCK) ? bucket_cnt[t] : 0;
    lds[t] = v;
    __syncthreads();
    for (int off = 1; off < 512; off <<= 1) {
        int x = (t >= off) ? lds[t - off] : 0;
        __syncthreads();
        lds[t] += x;
        __syncthreads();
    }
    int excl = lds[t] - v;
    if (t < NBUCK) { bucket_base[t] = excl; bucket_cursor[t] = excl; }
    if (t == 0) { bucket_base[NBUCK] = lds[NBUCK - 1]; rowptr[N_NODES] = N_EDGES; }
}

// ---- pass 3: bucketed scatter (hist from pass 1; one per-edge loop only) ----
__global__ void k_bscatter(const void* __restrict__ ei, const void* __restrict__ ew,
                           const int* __restrict__ flags, int* __restrict__ bucket_cursor,
                           uint2* __restrict__ ebuf, const int* __restrict__ blockhist, int e) {
    __shared__ int h[NBUCK];
    const int* bh = blockhist + (size_t)blockIdx.x * NBUCK;
    for (int t = threadIdx.x; t < NBUCK; t += 256) {
        int c = bh[t];
        h[t] = c ? atomicAdd(&bucket_cursor[t], c) : 0;  // claim contiguous chunk
    }
    __syncthreads();
    int f32m = flags[0], i64m = flags[1];
    int base = blockIdx.x * CHUNK;
    int end = base + CHUNK < e ? base + CHUNK : e;
    for (int i = base + threadIdx.x; i < end; i += 256) {
        int s = load_idx(ei, i, i64m);
        int d = load_idx(ei, (long long)N_EDGES + i, i64m);
        float w = load_f(ew, i, f32m);
        int b = d >> 8;
        int p = atomicAdd(&h[b], 1);  // LDS cursor holds global position
        uint2 c; c.x = (unsigned int)s | ((unsigned int)(d & 255) << 17); c.y = asu(w);
        ebuf[p] = c;
    }
}

// ---- pass 4: per-bucket fine sort -> final CSR + rowptr + dinv (zero global atomics) ----
// 512 threads: edge passes use all, node-local arrays are 256-wide.
__global__ void k_fine(const uint2* __restrict__ ebuf, const int* __restrict__ bucket_base,
                       uint2* __restrict__ csr, int* __restrict__ rowptr,
                       float* __restrict__ dinv, int n) {
    __shared__ int h[256];
    __shared__ float fw[256];
    __shared__ int c2[256];
    int t = threadIdx.x, b = blockIdx.x;
    int e0 = bucket_base[b], e1 = bucket_base[b + 1];
    if (t < 256) { h[t] = 0; fw[t] = 0.f; }
    __syncthreads();
    for (int i = e0 + t; i < e1; i += 512) {
        uint2 c = ebuf[i];
        int dl = (c.x >> 17) & 255;
        atomicAdd(&h[dl], 1);
        atomicAdd(&fw[dl], asf(c.y));
    }
    __syncthreads();
    int own = (t < 256) ? h[t] : 0;
    for (int off = 1; off < 256; off <<= 1) {
        int x = (t >= off && t < 256) ? h[t - off] : 0;
        __syncthreads();
        if (t < 256) h[t] += x;
        __syncthreads();
    }
    if (t < 256) {
        int excl = h[t] - own;
        int node = (b << 8) + t;
        if (node < n) {
            rowptr[node] = e0 + excl;
            dinv[node] = rsqrtf(1.0f + fw[t]);  // self-loop weight 1
        }
        c2[t] = e0 + excl;
    }
    __syncthreads();
    for (int i = e0 + t; i < e1; i += 512) {
        uint2 c = ebuf[i];
        int dl = (c.x >> 17) & 255;
        int p = atomicAdd(&c2[dl], 1);
        csr[p] = c;
    }
}

// ---- pass 5: fold dinv[src] into csr weights (streaming, 2 edges/thread) ----
__global__ void k_fold(uint4* __restrict__ csr4, const float* __restrict__ dinv, int npair) {
    int i = blockIdx.x * 256 + threadIdx.x;
    if (i >= npair) return;
    uint4 c = csr4[i];
    c.y = asu(asf(c.y) * dinv[c.x & 0x1FFFF]);
    c.w = asu(asf(c.w) * dinv[c.z & 0x1FFFF]);
    csr4[i] = c;
}

// ---------------- weight transpose → bf16 ----------------
__global__ void k_transpose(const void* __restrict__ W1, const void* __restrict__ W2,
                            const int* __restrict__ flags,
                            unsigned short* __restrict__ W1T, unsigned short* __restrict__ W2T) {
    int i = blockIdx.x * 256 + threadIdx.x;
    int f32m = flags[0];
    if (i < IN_DIM * HID_DIM) {
        int k = i / HID_DIM, n = i % HID_DIM;
        W1T[n * IN_DIM + k] = f2bf(load_f(W1, i, f32m));
    } else {
        int j = i - IN_DIM * HID_DIM;
        if (j < HID_DIM * OUT_DIM) {
            int k = j / OUT_DIM, n = j % OUT_DIM;
            W2T[n * HID_DIM + k] = f2bf(load_f(W2, j, f32m));
        }
    }
}

// ---------------- GEMM: H[n,128] = A[n,K] @ W[K,128], MFMA 16x16x32 bf16 ----------------
// Block: 4 waves, 64 rows (wave = ONE 16-row tile x 128 cols). Grid 1563 -> ~6 blk/CU,
// LDS 32KB caps 5 blk/CU = 20 waves/CU. Full K-half of A loaded up-front per wave;
// B staged in LDS with per-col chunk-rotation swizzle.
template <int KH, bool F32M>
__device__ __forceinline__ void gemm_loop(const void* __restrict__ A,
                                          const unsigned short* __restrict__ Bs,
                                          size_t aoff, int quad, int l16, floatx4 (&acc)[8]) {
    constexpr int NCH = KH / 32;
    constexpr int BMASK = KH / 8 - 1;
    short8 a[NCH];
    if (F32M) {
        const float* ap = (const float*)A;
#pragma unroll
        for (int ch = 0; ch < NCH; ch++) {
            float4 f0 = *(const float4*)(ap + aoff + ch * 32);
            float4 f1 = *(const float4*)(ap + aoff + ch * 32 + 4);
            a[ch] = pack8(f0, f1);
        }
    } else {
        const unsigned short* ap = (const unsigned short*)A;
#pragma unroll
        for (int ch = 0; ch < NCH; ch++)
            a[ch] = *(const short8*)(ap + aoff + ch * 32);
    }
#pragma unroll
    for (int ch = 0; ch < NCH; ch++) {
#pragma unroll
        for (int c = 0; c < 8; c++) {
            int col = c * 16 + l16;
            int boff = col * KH + 8 * ((ch * 4 + quad + (col & 7)) & BMASK);
            short8 bf = *(const short8*)(Bs + boff);
            acc[c] = __builtin_amdgcn_mfma_f32_16x16x32_bf16(a[ch], bf, acc[c], 0, 0, 0);
        }
    }
}

template <int K, bool RAWA>
__global__ void k_gemm(const void* __restrict__ A, const unsigned short* __restrict__ WT,
                       unsigned short* __restrict__ H, const int* __restrict__ flags, int n) {
    constexpr int KH = (K > 128) ? 128 : K;       // staging width (32KB LDS)
    __shared__ unsigned short Bs[128 * KH];

    int wave = threadIdx.x >> 6;
    int lane = threadIdx.x & 63;
    int quad = lane >> 4;
    int l16 = lane & 15;
    int rowbase = blockIdx.x * 64 + wave * 16;
    int r0 = rowbase + l16;        if (r0 >= n) r0 = n - 1;
    size_t aoff0 = (size_t)r0 * K + quad * 8;

    floatx4 acc[8];
#pragma unroll
    for (int c = 0; c < 8; c++) acc[c] = (floatx4){0.f, 0.f, 0.f, 0.f};

    int f32m = RAWA ? flags[0] : 0;

#pragma unroll
    for (int hh = 0; hh < K / KH; hh++) {
        if (hh) __syncthreads();   // all waves done reading previous half
        for (int base = threadIdx.x * 8; base < 128 * KH; base += 256 * 8) {
            int col = base / KH;
            int k = base - col * KH;
            int ks = (k + (col & 7) * 8) & (KH - 1);
            *(short8*)(&Bs[col * KH + ks]) = *(const short8*)(WT + col * K + hh * KH + k);
        }
        __syncthreads();
        if (RAWA && f32m)
            gemm_loop<KH, true>(A, Bs, aoff0 + hh * KH, quad, l16, acc);
        else
            gemm_loop<KH, false>(A, Bs, aoff0 + hh * KH, quad, l16, acc);
    }

#pragma unroll
    for (int c = 0; c < 8; c++)
#pragma unroll
        for (int r = 0; r < 4; r++) {
            int grow = rowbase + quad * 4 + r;
            if (grow < n) H[(size_t)grow * 128 + c * 16 + l16] = f2bf(acc[c][r]);
        }
}

// ---------------- aggregation ----------------
// out[n] = dinv[n]*sum_e (w')*h[src] + dinv[n]^2*h[n] + b   where w' = w*dinv[src] (pre-folded)
// Work-stealing (balance) + 2-stage 4-edge software pipeline (latency): ~8 H-gathers
// in flight per 16-lane group. VGPR ~44-48 still allows 8 waves/SIMD (cap is 64).
#define NODES_PER_BLK 32

__device__ __forceinline__ void acc8(float wt, uint4 hv, float* a) {
    a[0] += wt * bflo(hv.x); a[1] += wt * bfhi(hv.x);
    a[2] += wt * bflo(hv.y); a[3] += wt * bfhi(hv.y);
    a[4] += wt * bflo(hv.z); a[5] += wt * bfhi(hv.z);
    a[6] += wt * bflo(hv.w); a[7] += wt * bfhi(hv.w);
}

template <bool RELU, bool FINAL>
__global__ void k_aggregate(const unsigned short* __restrict__ H, const int* __restrict__ rowptr,
                            const uint2* __restrict__ csr, const float* __restrict__ dinv,
                            const void* __restrict__ bias, void* __restrict__ out,
                            const int* __restrict__ flags, int n) {
    __shared__ int cursor;
    if (threadIdx.x == 0) cursor = 0;
    __syncthreads();
    int lane = threadIdx.x & 15;
    int col = lane * 8;
    int f32m = flags[0];

    // bias hoisted: loaded once per thread, reused for every node
    float bv[8];
#pragma unroll
    for (int i = 0; i < 8; i++) bv[i] = load_f(bias, col + i, f32m);

    for (;;) {
        int idx;
        if (lane == 0) idx = atomicAdd(&cursor, 1);
        idx = __shfl(idx, 0, 16);
        if (idx >= NODES_PER_BLK) break;
        int node = blockIdx.x * NODES_PER_BLK + idx;
        if (node >= n) break;  // idx monotone per group -> all later pops also OOB

        int e0 = rowptr[node], e1 = rowptr[node + 1];
        uint4 u = *(const uint4*)(H + (size_t)node * 128 + col);  // self-row, early
        float dn = dinv[node];

        float a[8] = {0.f, 0.f, 0.f, 0.f, 0.f, 0.f, 0.f, 0.f};
        const uint2* ep = csr + e0;
        int nb = (e1 - e0) >> 2;
        uint2 c0, c1, c2, c3;
        uint4 h0, h1, h2, h3;
        if (nb) {  // prologue: batch 0 in flight
            c0 = ep[0]; c1 = ep[1]; c2 = ep[2]; c3 = ep[3];
            h0 = *(const uint4*)(H + (size_t)(c0.x & 0x1FFFF) * 128 + col);
            h1 = *(const uint4*)(H + (size_t)(c1.x & 0x1FFFF) * 128 + col);
            h2 = *(const uint4*)(H + (size_t)(c2.x & 0x1FFFF) * 128 + col);
            h3 = *(const uint4*)(H + (size_t)(c3.x & 0x1FFFF) * 128 + col);
        }
        for (int b = 1; b < nb; b++) {  // issue batch b while accumulating batch b-1
            const uint2* np = ep + 4 * b;
            uint2 d0 = np[0], d1 = np[1], d2 = np[2], d3 = np[3];
            uint4 g0 = *(const uint4*)(H + (size_t)(d0.x & 0x1FFFF) * 128 + col);
            uint4 g1 = *(const uint4*)(H + (size_t)(d1.x & 0x1FFFF) * 128 + col);
            uint4 g2 = *(const uint4*)(H + (size_t)(d2.x & 0x1FFFF) * 128 + col);
            uint4 g3 = *(const uint4*)(H + (size_t)(d3.x & 0x1FFFF) * 128 + col);
            acc8(asf(c0.y), h0, a); acc8(asf(c1.y), h1, a);
            acc8(asf(c2.y), h2, a); acc8(asf(c3.y), h3, a);
            c0 = d0; c1 = d1; c2 = d2; c3 = d3;
            h0 = g0; h1 = g1; h2 = g2; h3 = g3;
        }
        if (nb) {
            acc8(asf(c0.y), h0, a); acc8(asf(c1.y), h1, a);
            acc8(asf(c2.y), h2, a); acc8(asf(c3.y), h3, a);
        }
        for (int e = e0 + (nb << 2); e < e1; e++) {  // tail (<=3 edges)
            uint2 c = csr[e];
            uint4 hh = *(const uint4*)(H + (size_t)(c.x & 0x1FFFF) * 128 + col);
            acc8(asf(c.y), hh, a);
        }

        float coef = dn * dn;
        a[0] = dn * a[0] + coef * bflo(u.x) + bv[0];
        a[1] = dn * a[1] + coef * bfhi(u.x) + bv[1];
        a[2] = dn * a[2] + coef * bflo(u.y) + bv[2];
        a[3] = dn * a[3] + coef * bfhi(u.y) + bv[3];
        a[4] = dn * a[4] + coef * bflo(u.z) + bv[4];
        a[5] = dn * a[5] + coef * bfhi(u.z) + bv[5];
        a[6] = dn * a[6] + coef * bflo(u.w) + bv[6];
        a[7] = dn * a[7] + coef * bfhi(u.w) + bv[7];

        if (RELU) {
#pragma unroll
            for (int i = 0; i < 8; i++) a[i] = fmaxf(a[i], 0.f);
        }
        if (FINAL && f32m) {
            float* op = (float*)out + (size_t)node * 128 + col;
            float4 o0 = {a[0], a[1], a[2], a[3]};
            float4 o1 = {a[4], a[5], a[6], a[7]};
            *(float4*)op = o0;
            *(float4*)(op + 4) = o1;
        } else {
            uint4 o;
            o.x = pack2(a[0], a[1]); o.y = pack2(a[2], a[3]);
            o.z = pack2(a[4], a[5]); o.w = pack2(a[6], a[7]);
            *(uint4*)((unsigned short*)out + (size_t)node * 128 + col) = o;
        }
    }
}

extern "C" void kernel_launch(void* const* d_in, const int* in_sizes, int n_in,
                              void* d_out, int out_size, void* d_ws, size_t ws_size,
                              hipStream_t stream) {
    const void* x  = d_in[0];
    const void* ei = d_in[1];
    const void* ew = d_in[2];
    const void* W1 = d_in[3];
    const void* b1 = d_in[4];
    const void* W2 = d_in[5];
    const void* b2 = d_in[6];

    char* p = (char*)d_ws;
    auto alloc = [&](size_t bytes) { char* r = p; p += (bytes + 255) & ~(size_t)255; return r; };
    int*   flags    = (int*)alloc(256);
    float* dinv     = (float*)alloc((size_t)N_NODES * 4);
    int*   rowptr   = (int*)alloc((size_t)(N_NODES + 1) * 4);
    int*   bucket_cnt    = (int*)alloc((size_t)NBUCK * 4);
    int*   bucket_base   = (int*)alloc((size_t)(NBUCK + 1) * 4);
    int*   bucket_cursor = (int*)alloc((size_t)NBUCK * 4);
    uint2* csr      = (uint2*)alloc((size_t)N_EDGES * 8);
    unsigned short* W1T  = (unsigned short*)alloc((size_t)IN_DIM * HID_DIM * 2);
    unsigned short* W2T  = (unsigned short*)alloc((size_t)HID_DIM * OUT_DIM * 2);
    unsigned short* hbuf = (unsigned short*)alloc((size_t)N_NODES * 128 * 2);
    unsigned short* zbuf = (unsigned short*)alloc((size_t)N_NODES * 128 * 2);
    int nbC = (N_EDGES + CHUNK - 1) / CHUNK;                  // 782
    int*   blockhist = (int*)alloc((size_t)nbC * NBUCK * 4);  // 1.2 MB
    uint2* ebuf = (uint2*)hbuf;  // alias: ebuf dead before gemm1 writes hbuf

    int nbG = (N_NODES + 63) / 64;                            // 1563
    int nbA = (N_NODES + NODES_PER_BLK - 1) / NODES_PER_BLK;  // 3125
    int nbF = (N_EDGES / 2 + 255) / 256;                      // 3125

    k_detect<<<1, 512, 0, stream>>>((const unsigned int*)x, (const unsigned int*)ei, flags, bucket_cnt);
    k_bhist<<<nbC, 256, 0, stream>>>(ei, flags, bucket_cnt, blockhist, N_EDGES);
    k_bscan<<<1, 512, 0, stream>>>(bucket_cnt, bucket_base, bucket_cursor, rowptr);
    k_bscatter<<<nbC, 256, 0, stream>>>(ei, ew, flags, bucket_cursor, ebuf, blockhist, N_EDGES);
    k_fine<<<NBUCK, 512, 0, stream>>>(ebuf, bucket_base, csr, rowptr, dinv, N_NODES);
    k_fold<<<nbF, 256, 0, stream>>>((uint4*)csr, dinv, N_EDGES / 2);
    k_transpose<<<(IN_DIM * HID_DIM + HID_DIM * OUT_DIM + 255) / 256, 256, 0, stream>>>(W1, W2, flags, W1T, W2T);

    k_gemm<IN_DIM, true><<<nbG, 256, 0, stream>>>(x, W1T, hbuf, flags, N_NODES);
    k_aggregate<true, false><<<nbA, 256, 0, stream>>>(hbuf, rowptr, csr, dinv,
                                                      b1, zbuf, flags, N_NODES);
    k_gemm<HID_DIM, false><<<nbG, 256, 0, stream>>>(zbuf, W2T, hbuf, flags, N_NODES);
    k_aggregate<false, true><<<nbA, 256, 0, stream>>>(hbuf, rowptr, csr, dinv,
                                                      b2, d_out, flags, N_NODES);
}

// Round 7
// 442.082 us; speedup vs baseline: 1.0536x; 1.0536x over previous
//
#include <hip/hip_runtime.h>
#include <stdint.h>

#define N_NODES 100000
#define N_EDGES 1600000
#define IN_DIM 256
#define HID_DIM 128
#define OUT_DIM 128

#define NBUCK 391        // ceil(100000/256) buckets of 256 nodes
#define CHUNK 2048       // edges per block in bucket passes (782 blocks -> 3/CU)

typedef __attribute__((ext_vector_type(8))) short short8;
typedef __attribute__((ext_vector_type(4))) float floatx4;

__device__ __forceinline__ float bf2f(unsigned short u) {
    union { unsigned int i; float f; } v; v.i = ((unsigned int)u) << 16; return v.f;
}
__device__ __forceinline__ unsigned short f2bf(float f) {
    union { float fl; unsigned int i; } v; v.fl = f;
    unsigned int x = v.i;
    return (unsigned short)((x + 0x7fffu + ((x >> 16) & 1u)) >> 16);
}
__device__ __forceinline__ float bflo(unsigned int u) {
    union { unsigned int i; float f; } v; v.i = u << 16; return v.f;
}
__device__ __forceinline__ float bfhi(unsigned int u) {
    union { unsigned int i; float f; } v; v.i = u & 0xffff0000u; return v.f;
}
__device__ __forceinline__ float asf(unsigned int u) {
    union { unsigned int i; float f; } v; v.i = u; return v.f;
}
__device__ __forceinline__ unsigned int asu(float f) {
    union { float fl; unsigned int i; } v; v.fl = f; return v.i;
}
// two f32 -> packed bf16x2 (RNE)
__device__ __forceinline__ unsigned int pack2(float a, float b) {
    unsigned int ua = asu(a), ub = asu(b);
    ua += 0x7fffu + ((ua >> 16) & 1u);
    ub += 0x7fffu + ((ub >> 16) & 1u);
    return (ua >> 16) | (ub & 0xffff0000u);
}
__device__ __forceinline__ short8 pack8(float4 a, float4 b) {
    union { unsigned int u[4]; short8 s; } r;
    r.u[0] = pack2(a.x, a.y);
    r.u[1] = pack2(a.z, a.w);
    r.u[2] = pack2(b.x, b.y);
    r.u[3] = pack2(b.z, b.w);
    return r.s;
}

// Runtime input-dtype probes: flags[0]=1 if floats are f32 (else bf16); flags[1]=1 if idx i64.
// Also zeroes bucket_cnt (folded k_zero).
__global__ void k_detect(const unsigned int* __restrict__ xu, const unsigned int* __restrict__ eu,
                         int* __restrict__ flags, int* __restrict__ bucket_cnt) {
    __shared__ int s_huge, s_odd;
    if (threadIdx.x == 0) { s_huge = 0; s_odd = 0; }
    if (threadIdx.x < NBUCK) bucket_cnt[threadIdx.x] = 0;
    __syncthreads();
    int huge = 0, odd = 0;
    for (int i = threadIdx.x; i < 1024; i += 512) {
        unsigned int b = xu[i];
        unsigned int e = (b >> 23) & 0xffu;
        if (e >= 0xf0u) huge = 1;
        if (eu[2 * i + 1] != 0) odd = 1;
    }
    if (huge) atomicOr(&s_huge, 1);
    if (odd) atomicOr(&s_odd, 1);
    __syncthreads();
    if (threadIdx.x == 0) { flags[0] = s_huge ? 0 : 1; flags[1] = s_odd ? 0 : 1; }
}

__device__ __forceinline__ int load_idx(const void* base, long long i, int i64m) {
    int v = i64m ? (int)((const long long*)base)[i] : ((const int*)base)[i];
    return v < 0 ? 0 : (v >= N_NODES ? N_NODES - 1 : v);
}
__device__ __forceinline__ float load_f(const void* base, long long i, int f32m) {
    return f32m ? ((const float*)base)[i] : bf2f(((const unsigned short*)base)[i]);
}

// ---- pass 1: bucket histogram; per-block hist saved for bscatter reuse ----
__global__ void k_bhist(const void* __restrict__ ei, const int* __restrict__ flags,
                        int* __restrict__ bucket_cnt, int* __restrict__ blockhist, int e) {
    __shared__ int h[NBUCK];
    for (int t = threadIdx.x; t < NBUCK; t += 256) h[t] = 0;
    __syncthreads();
    int i64m = flags[1];
    int base = blockIdx.x * CHUNK;
    int end = base + CHUNK < e ? base + CHUNK : e;
    for (int i = base + threadIdx.x; i < end; i += 256) {
        int d = load_idx(ei, (long long)N_EDGES + i, i64m);
        atomicAdd(&h[d >> 8], 1);
    }
    __syncthreads();
    int* bh = blockhist + (size_t)blockIdx.x * NBUCK;
    for (int t = threadIdx.x; t < NBUCK; t += 256) {
        int v = h[t];
        bh[t] = v;
        if (v) atomicAdd(&bucket_cnt[t], v);
    }
}

// ---- pass 2: scan bucket counts -> bases & cursors (1 block) ----
__global__ void k_bscan(const int* __restrict__ bucket_cnt, int* __restrict__ bucket_base,
                        int* __restrict__ bucket_cursor, int* __restrict__ rowptr) {
    __shared__ int lds[512];
    int t = threadIdx.x;
    int v = (t < NBUCK) ? bucket_cnt[t] : 0;
    lds[t] = v;
    __syncthreads();
    for (int off = 1; off < 512; off <<= 1) {
        int x = (t >= off) ? lds[t - off] : 0;
        __syncthreads();
        lds[t] += x;
        __syncthreads();
    }
    int excl = lds[t] - v;
    if (t < NBUCK) { bucket_base[t] = excl; bucket_cursor[t] = excl; }
    if (t == 0) { bucket_base[NBUCK] = lds[NBUCK - 1]; rowptr[N_NODES] = N_EDGES; }
}

// ---- pass 3: bucketed scatter (hist from pass 1; one per-edge loop only) ----
__global__ void k_bscatter(const void* __restrict__ ei, const void* __restrict__ ew,
                           const int* __restrict__ flags, int* __restrict__ bucket_cursor,
                           uint2* __restrict__ ebuf, const int* __restrict__ blockhist, int e) {
    __shared__ int h[NBUCK];
    const int* bh = blockhist + (size_t)blockIdx.x * NBUCK;
    for (int t = threadIdx.x; t < NBUCK; t += 256) {
        int c = bh[t];
        h[t] = c ? atomicAdd(&bucket_cursor[t], c) : 0;  // claim contiguous chunk
    }
    __syncthreads();
    int f32m = flags[0], i64m = flags[1];
    int base = blockIdx.x * CHUNK;
    int end = base + CHUNK < e ? base + CHUNK : e;
    for (int i = base + threadIdx.x; i < end; i += 256) {
        int s = load_idx(ei, i, i64m);
        int d = load_idx(ei, (long long)N_EDGES + i, i64m);
        float w = load_f(ew, i, f32m);
        int b = d >> 8;
        int p = atomicAdd(&h[b], 1);  // LDS cursor holds global position
        uint2 c; c.x = (unsigned int)s | ((unsigned int)(d & 255) << 17); c.y = asu(w);
        ebuf[p] = c;
    }
}

// ---- pass 4: per-bucket fine sort -> final CSR + rowptr + dinv (zero global atomics) ----
// 512 threads: edge passes use all, node-local arrays are 256-wide.
__global__ void k_fine(const uint2* __restrict__ ebuf, const int* __restrict__ bucket_base,
                       uint2* __restrict__ csr, int* __restrict__ rowptr,
                       float* __restrict__ dinv, int n) {
    __shared__ int h[256];
    __shared__ float fw[256];
    __shared__ int c2[256];
    int t = threadIdx.x, b = blockIdx.x;
    int e0 = bucket_base[b], e1 = bucket_base[b + 1];
    if (t < 256) { h[t] = 0; fw[t] = 0.f; }
    __syncthreads();
    for (int i = e0 + t; i < e1; i += 512) {
        uint2 c = ebuf[i];
        int dl = (c.x >> 17) & 255;
        atomicAdd(&h[dl], 1);
        atomicAdd(&fw[dl], asf(c.y));
    }
    __syncthreads();
    int own = (t < 256) ? h[t] : 0;
    for (int off = 1; off < 256; off <<= 1) {
        int x = (t >= off && t < 256) ? h[t - off] : 0;
        __syncthreads();
        if (t < 256) h[t] += x;
        __syncthreads();
    }
    if (t < 256) {
        int excl = h[t] - own;
        int node = (b << 8) + t;
        if (node < n) {
            rowptr[node] = e0 + excl;
            dinv[node] = rsqrtf(1.0f + fw[t]);  // self-loop weight 1
        }
        c2[t] = e0 + excl;
    }
    __syncthreads();
    for (int i = e0 + t; i < e1; i += 512) {
        uint2 c = ebuf[i];
        int dl = (c.x >> 17) & 255;
        int p = atomicAdd(&c2[dl], 1);
        csr[p] = c;
    }
}

// ---------------- weight transpose → bf16 ----------------
__global__ void k_transpose(const void* __restrict__ W1, const void* __restrict__ W2,
                            const int* __restrict__ flags,
                            unsigned short* __restrict__ W1T, unsigned short* __restrict__ W2T) {
    int i = blockIdx.x * 256 + threadIdx.x;
    int f32m = flags[0];
    if (i < IN_DIM * HID_DIM) {
        int k = i / HID_DIM, n = i % HID_DIM;
        W1T[n * IN_DIM + k] = f2bf(load_f(W1, i, f32m));
    } else {
        int j = i - IN_DIM * HID_DIM;
        if (j < HID_DIM * OUT_DIM) {
            int k = j / OUT_DIM, n = j % OUT_DIM;
            W2T[n * HID_DIM + k] = f2bf(load_f(W2, j, f32m));
        }
    }
}

// ---------------- GEMM: H[n,128] = dinv[n] * (A[n,K] @ W[K,128]), MFMA 16x16x32 bf16 ----
// dinv row-scaling folded into the epilogue (replaces the k_fold pass: the aggregate
// then needs only raw edge weights).
// Block: 4 waves, 64 rows (wave = ONE 16-row tile x 128 cols). KH=64 -> Bs 16KB LDS
// -> 8 blocks/CU -> 32 waves/CU (hardware cap). Full K-quarter of A loaded up-front.
template <int KH, bool F32M>
__device__ __forceinline__ void gemm_loop(const void* __restrict__ A,
                                          const unsigned short* __restrict__ Bs,
                                          size_t aoff, int quad, int l16, floatx4 (&acc)[8]) {
    constexpr int NCH = KH / 32;
    constexpr int BMASK = KH / 8 - 1;
    short8 a[NCH];
    if (F32M) {
        const float* ap = (const float*)A;
#pragma unroll
        for (int ch = 0; ch < NCH; ch++) {
            float4 f0 = *(const float4*)(ap + aoff + ch * 32);
            float4 f1 = *(const float4*)(ap + aoff + ch * 32 + 4);
            a[ch] = pack8(f0, f1);
        }
    } else {
        const unsigned short* ap = (const unsigned short*)A;
#pragma unroll
        for (int ch = 0; ch < NCH; ch++)
            a[ch] = *(const short8*)(ap + aoff + ch * 32);
    }
#pragma unroll
    for (int ch = 0; ch < NCH; ch++) {
#pragma unroll
        for (int c = 0; c < 8; c++) {
            int col = c * 16 + l16;
            int boff = col * KH + 8 * ((ch * 4 + quad + (col & 7)) & BMASK);
            short8 bf = *(const short8*)(Bs + boff);
            acc[c] = __builtin_amdgcn_mfma_f32_16x16x32_bf16(a[ch], bf, acc[c], 0, 0, 0);
        }
    }
}

template <int K, bool RAWA>
__global__ void k_gemm(const void* __restrict__ A, const unsigned short* __restrict__ WT,
                       const float* __restrict__ dinv, unsigned short* __restrict__ H,
                       const int* __restrict__ flags, int n) {
    constexpr int KH = 64;                        // staging width (16KB LDS)
    __shared__ unsigned short Bs[128 * KH];

    int wave = threadIdx.x >> 6;
    int lane = threadIdx.x & 63;
    int quad = lane >> 4;
    int l16 = lane & 15;
    int rowbase = blockIdx.x * 64 + wave * 16;
    int r0 = rowbase + l16;        if (r0 >= n) r0 = n - 1;
    size_t aoff0 = (size_t)r0 * K + quad * 8;

    floatx4 acc[8];
#pragma unroll
    for (int c = 0; c < 8; c++) acc[c] = (floatx4){0.f, 0.f, 0.f, 0.f};

    int f32m = RAWA ? flags[0] : 0;

#pragma unroll
    for (int hh = 0; hh < K / KH; hh++) {
        if (hh) __syncthreads();   // all waves done reading previous quarter
        for (int base = threadIdx.x * 8; base < 128 * KH; base += 256 * 8) {
            int col = base / KH;
            int k = base - col * KH;
            int ks = (k + (col & 7) * 8) & (KH - 1);
            *(short8*)(&Bs[col * KH + ks]) = *(const short8*)(WT + col * K + hh * KH + k);
        }
        __syncthreads();
        if (RAWA && f32m)
            gemm_loop<KH, true>(A, Bs, aoff0 + hh * KH, quad, l16, acc);
        else
            gemm_loop<KH, false>(A, Bs, aoff0 + hh * KH, quad, l16, acc);
    }

#pragma unroll
    for (int r = 0; r < 4; r++) {
        int grow = rowbase + quad * 4 + r;
        if (grow < n) {
            float sc = dinv[grow];
#pragma unroll
            for (int c = 0; c < 8; c++)
                H[(size_t)grow * 128 + c * 16 + l16] = f2bf(sc * acc[c][r]);
        }
    }
}

// ---------------- aggregation ----------------
// H rows pre-scaled by dinv (in gemm epilogue), so:
// out[n] = dinv[n] * ( sum_e w * H'[src] + H'[n] ) + b      (opt ReLU)
// Work-stealing: 16 groups of 16 lanes pop nodes off an LDS cursor; simple 4-wide
// batches (VGPR ~36 -> full TLP; deeper ILP measured twice as a net loss).
#define NODES_PER_BLK 16

__device__ __forceinline__ void acc8(float wt, uint4 hv, float* a) {
    a[0] += wt * bflo(hv.x); a[1] += wt * bfhi(hv.x);
    a[2] += wt * bflo(hv.y); a[3] += wt * bfhi(hv.y);
    a[4] += wt * bflo(hv.z); a[5] += wt * bfhi(hv.z);
    a[6] += wt * bflo(hv.w); a[7] += wt * bfhi(hv.w);
}

template <bool RELU, bool FINAL>
__global__ void k_aggregate(const unsigned short* __restrict__ H, const int* __restrict__ rowptr,
                            const uint2* __restrict__ csr, const float* __restrict__ dinv,
                            const void* __restrict__ bias, void* __restrict__ out,
                            const int* __restrict__ flags, int n) {
    __shared__ int cursor;
    if (threadIdx.x == 0) cursor = 0;
    __syncthreads();
    int lane = threadIdx.x & 15;
    int col = lane * 8;
    int f32m = flags[0];

    // bias hoisted: loaded once per thread, reused for every node
    float bv[8];
#pragma unroll
    for (int i = 0; i < 8; i++) bv[i] = load_f(bias, col + i, f32m);

    for (;;) {
        int idx;
        if (lane == 0) idx = atomicAdd(&cursor, 1);
        idx = __shfl(idx, 0, 16);
        if (idx >= NODES_PER_BLK) break;
        int node = blockIdx.x * NODES_PER_BLK + idx;
        if (node >= n) break;  // idx monotone per group -> all later pops also OOB

        int e0 = rowptr[node], e1 = rowptr[node + 1];
        uint4 u = *(const uint4*)(H + (size_t)node * 128 + col);  // self-row, early
        float dn = dinv[node];

        float a[8] = {0.f, 0.f, 0.f, 0.f, 0.f, 0.f, 0.f, 0.f};
        int e = e0;
        for (; e + 4 <= e1; e += 4) {
            uint2 c0 = csr[e], c1 = csr[e + 1], c2 = csr[e + 2], c3 = csr[e + 3];
            uint4 h0 = *(const uint4*)(H + (size_t)(c0.x & 0x1FFFF) * 128 + col);
            uint4 h1 = *(const uint4*)(H + (size_t)(c1.x & 0x1FFFF) * 128 + col);
            uint4 h2 = *(const uint4*)(H + (size_t)(c2.x & 0x1FFFF) * 128 + col);
            uint4 h3 = *(const uint4*)(H + (size_t)(c3.x & 0x1FFFF) * 128 + col);
            acc8(asf(c0.y), h0, a); acc8(asf(c1.y), h1, a);
            acc8(asf(c2.y), h2, a); acc8(asf(c3.y), h3, a);
        }
        for (; e < e1; e++) {
            uint2 c = csr[e];
            uint4 hh = *(const uint4*)(H + (size_t)(c.x & 0x1FFFF) * 128 + col);
            acc8(asf(c.y), hh, a);
        }

        a[0] = dn * (a[0] + bflo(u.x)) + bv[0];
        a[1] = dn * (a[1] + bfhi(u.x)) + bv[1];
        a[2] = dn * (a[2] + bflo(u.y)) + bv[2];
        a[3] = dn * (a[3] + bfhi(u.y)) + bv[3];
        a[4] = dn * (a[4] + bflo(u.z)) + bv[4];
        a[5] = dn * (a[5] + bfhi(u.z)) + bv[5];
        a[6] = dn * (a[6] + bflo(u.w)) + bv[6];
        a[7] = dn * (a[7] + bfhi(u.w)) + bv[7];

        if (RELU) {
#pragma unroll
            for (int i = 0; i < 8; i++) a[i] = fmaxf(a[i], 0.f);
        }
        if (FINAL && f32m) {
            float* op = (float*)out + (size_t)node * 128 + col;
            float4 o0 = {a[0], a[1], a[2], a[3]};
            float4 o1 = {a[4], a[5], a[6], a[7]};
            *(float4*)op = o0;
            *(float4*)(op + 4) = o1;
        } else {
            uint4 o;
            o.x = pack2(a[0], a[1]); o.y = pack2(a[2], a[3]);
            o.z = pack2(a[4], a[5]); o.w = pack2(a[6], a[7]);
            *(uint4*)((unsigned short*)out + (size_t)node * 128 + col) = o;
        }
    }
}

extern "C" void kernel_launch(void* const* d_in, const int* in_sizes, int n_in,
                              void* d_out, int out_size, void* d_ws, size_t ws_size,
                              hipStream_t stream) {
    const void* x  = d_in[0];
    const void* ei = d_in[1];
    const void* ew = d_in[2];
    const void* W1 = d_in[3];
    const void* b1 = d_in[4];
    const void* W2 = d_in[5];
    const void* b2 = d_in[6];

    char* p = (char*)d_ws;
    auto alloc = [&](size_t bytes) { char* r = p; p += (bytes + 255) & ~(size_t)255; return r; };
    int*   flags    = (int*)alloc(256);
    float* dinv     = (float*)alloc((size_t)N_NODES * 4);
    int*   rowptr   = (int*)alloc((size_t)(N_NODES + 1) * 4);
    int*   bucket_cnt    = (int*)alloc((size_t)NBUCK * 4);
    int*   bucket_base   = (int*)alloc((size_t)(NBUCK + 1) * 4);
    int*   bucket_cursor = (int*)alloc((size_t)NBUCK * 4);
    uint2* csr      = (uint2*)alloc((size_t)N_EDGES * 8);
    unsigned short* W1T  = (unsigned short*)alloc((size_t)IN_DIM * HID_DIM * 2);
    unsigned short* W2T  = (unsigned short*)alloc((size_t)HID_DIM * OUT_DIM * 2);
    unsigned short* hbuf = (unsigned short*)alloc((size_t)N_NODES * 128 * 2);
    unsigned short* zbuf = (unsigned short*)alloc((size_t)N_NODES * 128 * 2);
    int nbC = (N_EDGES + CHUNK - 1) / CHUNK;                  // 782
    int*   blockhist = (int*)alloc((size_t)nbC * NBUCK * 4);  // 1.2 MB
    uint2* ebuf = (uint2*)hbuf;  // alias: ebuf dead before gemm1 writes hbuf

    int nbG = (N_NODES + 63) / 64;                            // 1563
    int nbA = (N_NODES + NODES_PER_BLK - 1) / NODES_PER_BLK;  // 6250

    k_detect<<<1, 512, 0, stream>>>((const unsigned int*)x, (const unsigned int*)ei, flags, bucket_cnt);
    k_bhist<<<nbC, 256, 0, stream>>>(ei, flags, bucket_cnt, blockhist, N_EDGES);
    k_bscan<<<1, 512, 0, stream>>>(bucket_cnt, bucket_base, bucket_cursor, rowptr);
    k_bscatter<<<nbC, 256, 0, stream>>>(ei, ew, flags, bucket_cursor, ebuf, blockhist, N_EDGES);
    k_fine<<<NBUCK, 512, 0, stream>>>(ebuf, bucket_base, csr, rowptr, dinv, N_NODES);
    k_transpose<<<(IN_DIM * HID_DIM + HID_DIM * OUT_DIM + 255) / 256, 256, 0, stream>>>(W1, W2, flags, W1T, W2T);

    k_gemm<IN_DIM, true><<<nbG, 256, 0, stream>>>(x, W1T, dinv, hbuf, flags, N_NODES);
    k_aggregate<true, false><<<nbA, 256, 0, stream>>>(hbuf, rowptr, csr, dinv,
                                                      b1, zbuf, flags, N_NODES);
    k_gemm<HID_DIM, false><<<nbG, 256, 0, stream>>>(zbuf, W2T, dinv, hbuf, flags, N_NODES);
    k_aggregate<false, true><<<nbA, 256, 0, stream>>>(hbuf, rowptr, csr, dinv,
                                                      b2, d_out, flags, N_NODES);
}

// Round 8
// 413.285 us; speedup vs baseline: 1.1271x; 1.0697x over previous
//
#include <hip/hip_runtime.h>
#include <stdint.h>

#define N_NODES 100000
#define N_EDGES 1600000
#define IN_DIM 256
#define HID_DIM 128
#define OUT_DIM 128

#define NBUCK 391        // ceil(100000/256) buckets of 256 nodes
#define CHUNK 4096       // edges per block in the scatter pass (391 blocks)
#define BCAP 4736        // padded bucket capacity: 4092 expected + 10 sigma

typedef __attribute__((ext_vector_type(8))) short short8;
typedef __attribute__((ext_vector_type(4))) float floatx4;

__device__ __forceinline__ float bf2f(unsigned short u) {
    union { unsigned int i; float f; } v; v.i = ((unsigned int)u) << 16; return v.f;
}
__device__ __forceinline__ unsigned short f2bf(float f) {
    union { float fl; unsigned int i; } v; v.fl = f;
    unsigned int x = v.i;
    return (unsigned short)((x + 0x7fffu + ((x >> 16) & 1u)) >> 16);
}
__device__ __forceinline__ float bflo(unsigned int u) {
    union { unsigned int i; float f; } v; v.i = u << 16; return v.f;
}
__device__ __forceinline__ float bfhi(unsigned int u) {
    union { unsigned int i; float f; } v; v.i = u & 0xffff0000u; return v.f;
}
__device__ __forceinline__ float asf(unsigned int u) {
    union { unsigned int i; float f; } v; v.i = u; return v.f;
}
__device__ __forceinline__ unsigned int asu(float f) {
    union { float fl; unsigned int i; } v; v.fl = f; return v.i;
}
// two f32 -> packed bf16x2 (RNE)
__device__ __forceinline__ unsigned int pack2(float a, float b) {
    unsigned int ua = asu(a), ub = asu(b);
    ua += 0x7fffu + ((ua >> 16) & 1u);
    ub += 0x7fffu + ((ub >> 16) & 1u);
    return (ua >> 16) | (ub & 0xffff0000u);
}
__device__ __forceinline__ short8 pack8(float4 a, float4 b) {
    union { unsigned int u[4]; short8 s; } r;
    r.u[0] = pack2(a.x, a.y);
    r.u[1] = pack2(a.z, a.w);
    r.u[2] = pack2(b.x, b.y);
    r.u[3] = pack2(b.z, b.w);
    return r.s;
}

// Runtime input-dtype probes: flags[0]=1 if floats are f32 (else bf16); flags[1]=1 if idx i64.
// Also zeroes bucket_cursor (folded zero pass).
__global__ void k_detect(const unsigned int* __restrict__ xu, const unsigned int* __restrict__ eu,
                         int* __restrict__ flags, int* __restrict__ bucket_cursor) {
    __shared__ int s_huge, s_odd;
    if (threadIdx.x == 0) { s_huge = 0; s_odd = 0; }
    if (threadIdx.x < NBUCK) bucket_cursor[threadIdx.x] = 0;
    __syncthreads();
    int huge = 0, odd = 0;
    for (int i = threadIdx.x; i < 1024; i += 512) {
        unsigned int b = xu[i];
        unsigned int e = (b >> 23) & 0xffu;
        if (e >= 0xf0u) huge = 1;
        if (eu[2 * i + 1] != 0) odd = 1;
    }
    if (huge) atomicOr(&s_huge, 1);
    if (odd) atomicOr(&s_odd, 1);
    __syncthreads();
    if (threadIdx.x == 0) { flags[0] = s_huge ? 0 : 1; flags[1] = s_odd ? 0 : 1; }
}

__device__ __forceinline__ int load_idx(const void* base, long long i, int i64m) {
    int v = i64m ? (int)((const long long*)base)[i] : ((const int*)base)[i];
    return v < 0 ? 0 : (v >= N_NODES ? N_NODES - 1 : v);
}
__device__ __forceinline__ float load_f(const void* base, long long i, int f32m) {
    return f32m ? ((const float*)base)[i] : bf2f(((const unsigned short*)base)[i]);
}

// ---- pass 1: bucketed scatter into PADDED bucket regions (no pre-histogram pass) ----
// Block: LDS hist over its chunk -> one global cursor claim per touched bucket ->
// scatter. Bucket b owns ebuf[b*BCAP .. b*BCAP+BCAP). Second read of dst-half is L2-hot.
__global__ void k_bscatter(const void* __restrict__ ei, const void* __restrict__ ew,
                           const int* __restrict__ flags, int* __restrict__ bucket_cursor,
                           uint2* __restrict__ ebuf, int e) {
    __shared__ int h[NBUCK];
    for (int t = threadIdx.x; t < NBUCK; t += 256) h[t] = 0;
    __syncthreads();
    int f32m = flags[0], i64m = flags[1];
    int base = blockIdx.x * CHUNK;
    int end = base + CHUNK < e ? base + CHUNK : e;
    for (int i = base + threadIdx.x; i < end; i += 256) {
        int d = load_idx(ei, (long long)N_EDGES + i, i64m);
        atomicAdd(&h[d >> 8], 1);
    }
    __syncthreads();
    for (int t = threadIdx.x; t < NBUCK; t += 256) {
        int c = h[t];
        h[t] = c ? (t * BCAP + atomicAdd(&bucket_cursor[t], c)) : 0;  // claim padded run
    }
    __syncthreads();
    for (int i = base + threadIdx.x; i < end; i += 256) {
        int s = load_idx(ei, i, i64m);
        int d = load_idx(ei, (long long)N_EDGES + i, i64m);
        float w = load_f(ew, i, f32m);
        int b = d >> 8;
        int p = atomicAdd(&h[b], 1);  // LDS cursor holds global (padded) position
        uint2 c; c.x = (unsigned int)s | ((unsigned int)(d & 255) << 17); c.y = asu(w);
        ebuf[p] = c;
    }
}

// ---- pass 2: scan bucket counts (= final cursors) -> compact bases; rowptr tail ----
__global__ void k_bscan(const int* __restrict__ bucket_cursor, int* __restrict__ bucket_base,
                        int* __restrict__ rowptr) {
    __shared__ int lds[512];
    int t = threadIdx.x;
    int v = (t < NBUCK) ? bucket_cursor[t] : 0;
    lds[t] = v;
    __syncthreads();
    for (int off = 1; off < 512; off <<= 1) {
        int x = (t >= off) ? lds[t - off] : 0;
        __syncthreads();
        lds[t] += x;
        __syncthreads();
    }
    int excl = lds[t] - v;
    if (t < NBUCK) bucket_base[t] = excl;
    if (t == 0) { bucket_base[NBUCK] = lds[NBUCK - 1]; rowptr[N_NODES] = N_EDGES; }
}

// ---- pass 3: per-bucket fine sort (padded region -> compact CSR) + rowptr + dinv ----
// 512 threads: edge passes use all, node-local arrays are 256-wide.
__global__ void k_fine(const uint2* __restrict__ ebuf, const int* __restrict__ bucket_base,
                       uint2* __restrict__ csr, int* __restrict__ rowptr,
                       float* __restrict__ dinv, int n) {
    __shared__ int h[256];
    __shared__ float fw[256];
    __shared__ int c2[256];
    int t = threadIdx.x, b = blockIdx.x;
    int w0 = bucket_base[b];
    int cnt = bucket_base[b + 1] - w0;
    const uint2* src = ebuf + (size_t)b * BCAP;
    if (t < 256) { h[t] = 0; fw[t] = 0.f; }
    __syncthreads();
    for (int i = t; i < cnt; i += 512) {
        uint2 c = src[i];
        int dl = (c.x >> 17) & 255;
        atomicAdd(&h[dl], 1);
        atomicAdd(&fw[dl], asf(c.y));
    }
    __syncthreads();
    int own = (t < 256) ? h[t] : 0;
    for (int off = 1; off < 256; off <<= 1) {
        int x = (t >= off && t < 256) ? h[t - off] : 0;
        __syncthreads();
        if (t < 256) h[t] += x;
        __syncthreads();
    }
    if (t < 256) {
        int excl = h[t] - own;
        int node = (b << 8) + t;
        if (node < n) {
            rowptr[node] = w0 + excl;
            dinv[node] = rsqrtf(1.0f + fw[t]);  // self-loop weight 1
        }
        c2[t] = w0 + excl;
    }
    __syncthreads();
    for (int i = t; i < cnt; i += 512) {
        uint2 c = src[i];
        int dl = (c.x >> 17) & 255;
        int p = atomicAdd(&c2[dl], 1);
        csr[p] = c;
    }
}

// ---------------- weight transpose → bf16 ----------------
__global__ void k_transpose(const void* __restrict__ W1, const void* __restrict__ W2,
                            const int* __restrict__ flags,
                            unsigned short* __restrict__ W1T, unsigned short* __restrict__ W2T) {
    int i = blockIdx.x * 256 + threadIdx.x;
    int f32m = flags[0];
    if (i < IN_DIM * HID_DIM) {
        int k = i / HID_DIM, n = i % HID_DIM;
        W1T[n * IN_DIM + k] = f2bf(load_f(W1, i, f32m));
    } else {
        int j = i - IN_DIM * HID_DIM;
        if (j < HID_DIM * OUT_DIM) {
            int k = j / OUT_DIM, n = j % OUT_DIM;
            W2T[n * HID_DIM + k] = f2bf(load_f(W2, j, f32m));
        }
    }
}

// ---------------- GEMM: H[n,128] = dinv[n] * (A[n,K] @ W[K,128]), MFMA 16x16x32 bf16 ----
// dinv row-scaling folded into the epilogue (the aggregate then needs only raw weights).
// Block: 4 waves, 64 rows (wave = ONE 16-row tile x 128 cols). KH=64 -> Bs 16KB LDS
// -> 8 blocks/CU -> 32 waves/CU (hardware cap). Full K-quarter of A loaded up-front.
template <int KH, bool F32M>
__device__ __forceinline__ void gemm_loop(const void* __restrict__ A,
                                          const unsigned short* __restrict__ Bs,
                                          size_t aoff, int quad, int l16, floatx4 (&acc)[8]) {
    constexpr int NCH = KH / 32;
    constexpr int BMASK = KH / 8 - 1;
    short8 a[NCH];
    if (F32M) {
        const float* ap = (const float*)A;
#pragma unroll
        for (int ch = 0; ch < NCH; ch++) {
            float4 f0 = *(const float4*)(ap + aoff + ch * 32);
            float4 f1 = *(const float4*)(ap + aoff + ch * 32 + 4);
            a[ch] = pack8(f0, f1);
        }
    } else {
        const unsigned short* ap = (const unsigned short*)A;
#pragma unroll
        for (int ch = 0; ch < NCH; ch++)
            a[ch] = *(const short8*)(ap + aoff + ch * 32);
    }
#pragma unroll
    for (int ch = 0; ch < NCH; ch++) {
#pragma unroll
        for (int c = 0; c < 8; c++) {
            int col = c * 16 + l16;
            int boff = col * KH + 8 * ((ch * 4 + quad + (col & 7)) & BMASK);
            short8 bf = *(const short8*)(Bs + boff);
            acc[c] = __builtin_amdgcn_mfma_f32_16x16x32_bf16(a[ch], bf, acc[c], 0, 0, 0);
        }
    }
}

template <int K, bool RAWA>
__global__ void k_gemm(const void* __restrict__ A, const unsigned short* __restrict__ WT,
                       const float* __restrict__ dinv, unsigned short* __restrict__ H,
                       const int* __restrict__ flags, int n) {
    constexpr int KH = 64;                        // staging width (16KB LDS)
    __shared__ unsigned short Bs[128 * KH];

    int wave = threadIdx.x >> 6;
    int lane = threadIdx.x & 63;
    int quad = lane >> 4;
    int l16 = lane & 15;
    int rowbase = blockIdx.x * 64 + wave * 16;
    int r0 = rowbase + l16;        if (r0 >= n) r0 = n - 1;
    size_t aoff0 = (size_t)r0 * K + quad * 8;

    floatx4 acc[8];
#pragma unroll
    for (int c = 0; c < 8; c++) acc[c] = (floatx4){0.f, 0.f, 0.f, 0.f};

    int f32m = RAWA ? flags[0] : 0;

#pragma unroll
    for (int hh = 0; hh < K / KH; hh++) {
        if (hh) __syncthreads();   // all waves done reading previous quarter
        for (int base = threadIdx.x * 8; base < 128 * KH; base += 256 * 8) {
            int col = base / KH;
            int k = base - col * KH;
            int ks = (k + (col & 7) * 8) & (KH - 1);
            *(short8*)(&Bs[col * KH + ks]) = *(const short8*)(WT + col * K + hh * KH + k);
        }
        __syncthreads();
        if (RAWA && f32m)
            gemm_loop<KH, true>(A, Bs, aoff0 + hh * KH, quad, l16, acc);
        else
            gemm_loop<KH, false>(A, Bs, aoff0 + hh * KH, quad, l16, acc);
    }

#pragma unroll
    for (int r = 0; r < 4; r++) {
        int grow = rowbase + quad * 4 + r;
        if (grow < n) {
            float sc = dinv[grow];
#pragma unroll
            for (int c = 0; c < 8; c++)
                H[(size_t)grow * 128 + c * 16 + l16] = f2bf(sc * acc[c][r]);
        }
    }
}

// ---------------- aggregation ----------------
// H rows pre-scaled by dinv (in gemm epilogue), so:
// out[n] = dinv[n] * ( sum_e w * H'[src] + H'[n] ) + b      (opt ReLU)
// Work-stealing: 16 groups of 16 lanes pop nodes off an LDS cursor; simple 4-wide
// batches (VGPR ~36 -> full TLP; deeper ILP measured twice as a net loss).
// BW pinned at ~3.5 TB/s across occ 45-69% -> random-gather service ceiling.
#define NODES_PER_BLK 16

__device__ __forceinline__ void acc8(float wt, uint4 hv, float* a) {
    a[0] += wt * bflo(hv.x); a[1] += wt * bfhi(hv.x);
    a[2] += wt * bflo(hv.y); a[3] += wt * bfhi(hv.y);
    a[4] += wt * bflo(hv.z); a[5] += wt * bfhi(hv.z);
    a[6] += wt * bflo(hv.w); a[7] += wt * bfhi(hv.w);
}

template <bool RELU, bool FINAL>
__global__ void k_aggregate(const unsigned short* __restrict__ H, const int* __restrict__ rowptr,
                            const uint2* __restrict__ csr, const float* __restrict__ dinv,
                            const void* __restrict__ bias, void* __restrict__ out,
                            const int* __restrict__ flags, int n) {
    __shared__ int cursor;
    if (threadIdx.x == 0) cursor = 0;
    __syncthreads();
    int lane = threadIdx.x & 15;
    int col = lane * 8;
    int f32m = flags[0];

    // bias hoisted: loaded once per thread, reused for every node
    float bv[8];
#pragma unroll
    for (int i = 0; i < 8; i++) bv[i] = load_f(bias, col + i, f32m);

    for (;;) {
        int idx;
        if (lane == 0) idx = atomicAdd(&cursor, 1);
        idx = __shfl(idx, 0, 16);
        if (idx >= NODES_PER_BLK) break;
        int node = blockIdx.x * NODES_PER_BLK + idx;
        if (node >= n) break;  // idx monotone per group -> all later pops also OOB

        int e0 = rowptr[node], e1 = rowptr[node + 1];
        uint4 u = *(const uint4*)(H + (size_t)node * 128 + col);  // self-row, early
        float dn = dinv[node];

        float a[8] = {0.f, 0.f, 0.f, 0.f, 0.f, 0.f, 0.f, 0.f};
        int e = e0;
        for (; e + 4 <= e1; e += 4) {
            uint2 c0 = csr[e], c1 = csr[e + 1], c2 = csr[e + 2], c3 = csr[e + 3];
            uint4 h0 = *(const uint4*)(H + (size_t)(c0.x & 0x1FFFF) * 128 + col);
            uint4 h1 = *(const uint4*)(H + (size_t)(c1.x & 0x1FFFF) * 128 + col);
            uint4 h2 = *(const uint4*)(H + (size_t)(c2.x & 0x1FFFF) * 128 + col);
            uint4 h3 = *(const uint4*)(H + (size_t)(c3.x & 0x1FFFF) * 128 + col);
            acc8(asf(c0.y), h0, a); acc8(asf(c1.y), h1, a);
            acc8(asf(c2.y), h2, a); acc8(asf(c3.y), h3, a);
        }
        for (; e < e1; e++) {
            uint2 c = csr[e];
            uint4 hh = *(const uint4*)(H + (size_t)(c.x & 0x1FFFF) * 128 + col);
            acc8(asf(c.y), hh, a);
        }

        a[0] = dn * (a[0] + bflo(u.x)) + bv[0];
        a[1] = dn * (a[1] + bfhi(u.x)) + bv[1];
        a[2] = dn * (a[2] + bflo(u.y)) + bv[2];
        a[3] = dn * (a[3] + bfhi(u.y)) + bv[3];
        a[4] = dn * (a[4] + bflo(u.z)) + bv[4];
        a[5] = dn * (a[5] + bfhi(u.z)) + bv[5];
        a[6] = dn * (a[6] + bflo(u.w)) + bv[6];
        a[7] = dn * (a[7] + bfhi(u.w)) + bv[7];

        if (RELU) {
#pragma unroll
            for (int i = 0; i < 8; i++) a[i] = fmaxf(a[i], 0.f);
        }
        if (FINAL && f32m) {
            float* op = (float*)out + (size_t)node * 128 + col;
            float4 o0 = {a[0], a[1], a[2], a[3]};
            float4 o1 = {a[4], a[5], a[6], a[7]};
            *(float4*)op = o0;
            *(float4*)(op + 4) = o1;
        } else {
            uint4 o;
            o.x = pack2(a[0], a[1]); o.y = pack2(a[2], a[3]);
            o.z = pack2(a[4], a[5]); o.w = pack2(a[6], a[7]);
            *(uint4*)((unsigned short*)out + (size_t)node * 128 + col) = o;
        }
    }
}

extern "C" void kernel_launch(void* const* d_in, const int* in_sizes, int n_in,
                              void* d_out, int out_size, void* d_ws, size_t ws_size,
                              hipStream_t stream) {
    const void* x  = d_in[0];
    const void* ei = d_in[1];
    const void* ew = d_in[2];
    const void* W1 = d_in[3];
    const void* b1 = d_in[4];
    const void* W2 = d_in[5];
    const void* b2 = d_in[6];

    char* p = (char*)d_ws;
    auto alloc = [&](size_t bytes) { char* r = p; p += (bytes + 255) & ~(size_t)255; return r; };
    int*   flags    = (int*)alloc(256);
    float* dinv     = (float*)alloc((size_t)N_NODES * 4);
    int*   rowptr   = (int*)alloc((size_t)(N_NODES + 1) * 4);
    int*   bucket_cursor = (int*)alloc((size_t)NBUCK * 4);
    int*   bucket_base   = (int*)alloc((size_t)(NBUCK + 1) * 4);
    uint2* csr      = (uint2*)alloc((size_t)N_EDGES * 8);
    unsigned short* W1T  = (unsigned short*)alloc((size_t)IN_DIM * HID_DIM * 2);
    unsigned short* W2T  = (unsigned short*)alloc((size_t)HID_DIM * OUT_DIM * 2);
    unsigned short* hbuf = (unsigned short*)alloc((size_t)N_NODES * 128 * 2);
    unsigned short* zbuf = (unsigned short*)alloc((size_t)N_NODES * 128 * 2);
    uint2* ebuf = (uint2*)hbuf;  // padded bucket space: NBUCK*BCAP*8 = 14.8 MB < 25.6 MB

    int nbC = (N_EDGES + CHUNK - 1) / CHUNK;                  // 391
    int nbG = (N_NODES + 63) / 64;                            // 1563
    int nbA = (N_NODES + NODES_PER_BLK - 1) / NODES_PER_BLK;  // 6250

    k_detect<<<1, 512, 0, stream>>>((const unsigned int*)x, (const unsigned int*)ei, flags, bucket_cursor);
    k_bscatter<<<nbC, 256, 0, stream>>>(ei, ew, flags, bucket_cursor, ebuf, N_EDGES);
    k_bscan<<<1, 512, 0, stream>>>(bucket_cursor, bucket_base, rowptr);
    k_fine<<<NBUCK, 512, 0, stream>>>(ebuf, bucket_base, csr, rowptr, dinv, N_NODES);
    k_transpose<<<(IN_DIM * HID_DIM + HID_DIM * OUT_DIM + 255) / 256, 256, 0, stream>>>(W1, W2, flags, W1T, W2T);

    k_gemm<IN_DIM, true><<<nbG, 256, 0, stream>>>(x, W1T, dinv, hbuf, flags, N_NODES);
    k_aggregate<true, false><<<nbA, 256, 0, stream>>>(hbuf, rowptr, csr, dinv,
                                                      b1, zbuf, flags, N_NODES);
    k_gemm<HID_DIM, false><<<nbG, 256, 0, stream>>>(zbuf, W2T, dinv, hbuf, flags, N_NODES);
    k_aggregate<false, true><<<nbA, 256, 0, stream>>>(hbuf, rowptr, csr, dinv,
                                                      b2, d_out, flags, N_NODES);
}

// Round 9
// 412.740 us; speedup vs baseline: 1.1286x; 1.0013x over previous
//
#include <hip/hip_runtime.h>
#include <stdint.h>

#define N_NODES 100000
#define N_EDGES 1600000
#define IN_DIM 256
#define HID_DIM 128
#define OUT_DIM 128

#define NBUCK 391        // ceil(100000/256) buckets of 256 nodes
#define CHUNK 4096       // edges per block in the scatter pass (391 blocks)
#define BCAP 4736        // padded bucket capacity: 4092 expected + 10 sigma

typedef __attribute__((ext_vector_type(8))) short short8;
typedef __attribute__((ext_vector_type(4))) float floatx4;

__device__ __forceinline__ float bf2f(unsigned short u) {
    union { unsigned int i; float f; } v; v.i = ((unsigned int)u) << 16; return v.f;
}
__device__ __forceinline__ unsigned short f2bf(float f) {
    union { float fl; unsigned int i; } v; v.fl = f;
    unsigned int x = v.i;
    return (unsigned short)((x + 0x7fffu + ((x >> 16) & 1u)) >> 16);
}
__device__ __forceinline__ float bflo(unsigned int u) {
    union { unsigned int i; float f; } v; v.i = u << 16; return v.f;
}
__device__ __forceinline__ float bfhi(unsigned int u) {
    union { unsigned int i; float f; } v; v.i = u & 0xffff0000u; return v.f;
}
__device__ __forceinline__ float asf(unsigned int u) {
    union { unsigned int i; float f; } v; v.i = u; return v.f;
}
__device__ __forceinline__ unsigned int asu(float f) {
    union { float fl; unsigned int i; } v; v.fl = f; return v.i;
}
// two f32 -> packed bf16x2 (RNE)
__device__ __forceinline__ unsigned int pack2(float a, float b) {
    unsigned int ua = asu(a), ub = asu(b);
    ua += 0x7fffu + ((ua >> 16) & 1u);
    ub += 0x7fffu + ((ub >> 16) & 1u);
    return (ua >> 16) | (ub & 0xffff0000u);
}
__device__ __forceinline__ short8 pack8(float4 a, float4 b) {
    union { unsigned int u[4]; short8 s; } r;
    r.u[0] = pack2(a.x, a.y);
    r.u[1] = pack2(a.z, a.w);
    r.u[2] = pack2(b.x, b.y);
    r.u[3] = pack2(b.z, b.w);
    return r.s;
}

// Runtime input-dtype probes: flags[0]=1 if floats are f32 (else bf16); flags[1]=1 if idx i64.
// Also zeroes bucket_cursor (folded zero pass).
__global__ void k_detect(const unsigned int* __restrict__ xu, const unsigned int* __restrict__ eu,
                         int* __restrict__ flags, int* __restrict__ bucket_cursor) {
    __shared__ int s_huge, s_odd;
    if (threadIdx.x == 0) { s_huge = 0; s_odd = 0; }
    if (threadIdx.x < NBUCK) bucket_cursor[threadIdx.x] = 0;
    __syncthreads();
    int huge = 0, odd = 0;
    for (int i = threadIdx.x; i < 1024; i += 512) {
        unsigned int b = xu[i];
        unsigned int e = (b >> 23) & 0xffu;
        if (e >= 0xf0u) huge = 1;
        if (eu[2 * i + 1] != 0) odd = 1;
    }
    if (huge) atomicOr(&s_huge, 1);
    if (odd) atomicOr(&s_odd, 1);
    __syncthreads();
    if (threadIdx.x == 0) { flags[0] = s_huge ? 0 : 1; flags[1] = s_odd ? 0 : 1; }
}

__device__ __forceinline__ int load_idx(const void* base, long long i, int i64m) {
    int v = i64m ? (int)((const long long*)base)[i] : ((const int*)base)[i];
    return v < 0 ? 0 : (v >= N_NODES ? N_NODES - 1 : v);
}
__device__ __forceinline__ float load_f(const void* base, long long i, int f32m) {
    return f32m ? ((const float*)base)[i] : bf2f(((const unsigned short*)base)[i]);
}

// ---- pass 1: bucketed scatter into PADDED bucket regions (no pre-histogram pass) ----
__global__ void k_bscatter(const void* __restrict__ ei, const void* __restrict__ ew,
                           const int* __restrict__ flags, int* __restrict__ bucket_cursor,
                           uint2* __restrict__ ebuf, int e) {
    __shared__ int h[NBUCK];
    for (int t = threadIdx.x; t < NBUCK; t += 256) h[t] = 0;
    __syncthreads();
    int f32m = flags[0], i64m = flags[1];
    int base = blockIdx.x * CHUNK;
    int end = base + CHUNK < e ? base + CHUNK : e;
    for (int i = base + threadIdx.x; i < end; i += 256) {
        int d = load_idx(ei, (long long)N_EDGES + i, i64m);
        atomicAdd(&h[d >> 8], 1);
    }
    __syncthreads();
    for (int t = threadIdx.x; t < NBUCK; t += 256) {
        int c = h[t];
        h[t] = c ? (t * BCAP + atomicAdd(&bucket_cursor[t], c)) : 0;  // claim padded run
    }
    __syncthreads();
    for (int i = base + threadIdx.x; i < end; i += 256) {
        int s = load_idx(ei, i, i64m);
        int d = load_idx(ei, (long long)N_EDGES + i, i64m);
        float w = load_f(ew, i, f32m);
        int b = d >> 8;
        int p = atomicAdd(&h[b], 1);  // LDS cursor holds global (padded) position
        uint2 c; c.x = (unsigned int)s | ((unsigned int)(d & 255) << 17); c.y = asu(w);
        ebuf[p] = c;
    }
}

// ---- pass 2: scan bucket counts (= final cursors) -> compact bases; rowptr tail ----
__global__ void k_bscan(const int* __restrict__ bucket_cursor, int* __restrict__ bucket_base,
                        int* __restrict__ rowptr) {
    __shared__ int lds[512];
    int t = threadIdx.x;
    int v = (t < NBUCK) ? bucket_cursor[t] : 0;
    lds[t] = v;
    __syncthreads();
    for (int off = 1; off < 512; off <<= 1) {
        int x = (t >= off) ? lds[t - off] : 0;
        __syncthreads();
        lds[t] += x;
        __syncthreads();
    }
    int excl = lds[t] - v;
    if (t < NBUCK) bucket_base[t] = excl;
    if (t == 0) { bucket_base[NBUCK] = lds[NBUCK - 1]; rowptr[N_NODES] = N_EDGES; }
}

// ---- pass 3: per-bucket fine sort (padded region -> compact CSR) + rowptr + dinv ----
__global__ void k_fine(const uint2* __restrict__ ebuf, const int* __restrict__ bucket_base,
                       uint2* __restrict__ csr, int* __restrict__ rowptr,
                       float* __restrict__ dinv, int n) {
    __shared__ int h[256];
    __shared__ float fw[256];
    __shared__ int c2[256];
    int t = threadIdx.x, b = blockIdx.x;
    int w0 = bucket_base[b];
    int cnt = bucket_base[b + 1] - w0;
    const uint2* src = ebuf + (size_t)b * BCAP;
    if (t < 256) { h[t] = 0; fw[t] = 0.f; }
    __syncthreads();
    for (int i = t; i < cnt; i += 512) {
        uint2 c = src[i];
        int dl = (c.x >> 17) & 255;
        atomicAdd(&h[dl], 1);
        atomicAdd(&fw[dl], asf(c.y));
    }
    __syncthreads();
    int own = (t < 256) ? h[t] : 0;
    for (int off = 1; off < 256; off <<= 1) {
        int x = (t >= off && t < 256) ? h[t - off] : 0;
        __syncthreads();
        if (t < 256) h[t] += x;
        __syncthreads();
    }
    if (t < 256) {
        int excl = h[t] - own;
        int node = (b << 8) + t;
        if (node < n) {
            rowptr[node] = w0 + excl;
            dinv[node] = rsqrtf(1.0f + fw[t]);  // self-loop weight 1
        }
        c2[t] = w0 + excl;
    }
    __syncthreads();
    for (int i = t; i < cnt; i += 512) {
        uint2 c = src[i];
        int dl = (c.x >> 17) & 255;
        int p = atomicAdd(&c2[dl], 1);
        csr[p] = c;
    }
}

// ---------------- weight transpose → bf16 ----------------
__global__ void k_transpose(const void* __restrict__ W1, const void* __restrict__ W2,
                            const int* __restrict__ flags,
                            unsigned short* __restrict__ W1T, unsigned short* __restrict__ W2T) {
    int i = blockIdx.x * 256 + threadIdx.x;
    int f32m = flags[0];
    if (i < IN_DIM * HID_DIM) {
        int k = i / HID_DIM, n = i % HID_DIM;
        W1T[n * IN_DIM + k] = f2bf(load_f(W1, i, f32m));
    } else {
        int j = i - IN_DIM * HID_DIM;
        if (j < HID_DIM * OUT_DIM) {
            int k = j / OUT_DIM, n = j % OUT_DIM;
            W2T[n * HID_DIM + k] = f2bf(load_f(W2, j, f32m));
        }
    }
}

// ---------------- GEMM: H[n,128] = dinv[n] * (A[n,K] @ W[K,128]), MFMA 16x16x32 bf16 ----
// Barrier-free K-loop: ALL of B staged once in LDS (64KB K=256 / 32KB K=128, ONE
// __syncthreads), ALL of A preloaded to regs before the barrier (loads complete under
// the staging shadow). 512-thread blocks, 8 waves x 16 rows = 128 rows/block.
// LDS caps residency (2 blk/CU K=256, 4 blk/CU K=128) before VGPR does.
template <int K, bool RAWA>
__global__ void k_gemm(const void* __restrict__ A, const unsigned short* __restrict__ WT,
                       const float* __restrict__ dinv, unsigned short* __restrict__ H,
                       const int* __restrict__ flags, int n) {
    __shared__ unsigned short Bs[128 * K];
    constexpr int NCH = K / 32;
    constexpr int BMASK = K / 8 - 1;

    int wave = threadIdx.x >> 6;
    int lane = threadIdx.x & 63;
    int quad = lane >> 4;
    int l16 = lane & 15;
    int rowbase = blockIdx.x * 128 + wave * 16;
    int r0 = rowbase + l16;        if (r0 >= n) r0 = n - 1;
    size_t aoff = (size_t)r0 * K + quad * 8;

    // stage all of B (per-col chunk-rotation swizzle, consistent with read below)
    for (int base = threadIdx.x * 8; base < 128 * K; base += 512 * 8) {
        int col = base / K;
        int k = base - col * K;
        int ks = (k + (col & 7) * 8) & (K - 1);
        *(short8*)(&Bs[col * K + ks]) = *(const short8*)(WT + base);
    }

    // preload ALL of A for this lane's row (issued before the barrier; completes
    // under the staging+barrier shadow)
    short8 a[NCH];
    int f32m = RAWA ? flags[0] : 0;
    if (RAWA && f32m) {
        const float* ap = (const float*)A;
        float4 f[NCH][2];
#pragma unroll
        for (int ch = 0; ch < NCH; ch++) {
            f[ch][0] = *(const float4*)(ap + aoff + ch * 32);
            f[ch][1] = *(const float4*)(ap + aoff + ch * 32 + 4);
        }
#pragma unroll
        for (int ch = 0; ch < NCH; ch++) a[ch] = pack8(f[ch][0], f[ch][1]);
    } else {
        const unsigned short* ap = (const unsigned short*)A;
#pragma unroll
        for (int ch = 0; ch < NCH; ch++)
            a[ch] = *(const short8*)(ap + aoff + ch * 32);
    }

    __syncthreads();   // Bs ready — the only barrier in the kernel

    floatx4 acc[8];
#pragma unroll
    for (int c = 0; c < 8; c++) acc[c] = (floatx4){0.f, 0.f, 0.f, 0.f};

#pragma unroll
    for (int ch = 0; ch < NCH; ch++) {
#pragma unroll
        for (int c = 0; c < 8; c++) {
            int col = c * 16 + l16;
            int boff = col * K + 8 * ((ch * 4 + quad + (col & 7)) & BMASK);
            short8 bf = *(const short8*)(Bs + boff);
            acc[c] = __builtin_amdgcn_mfma_f32_16x16x32_bf16(a[ch], bf, acc[c], 0, 0, 0);
        }
    }

#pragma unroll
    for (int r = 0; r < 4; r++) {
        int grow = rowbase + quad * 4 + r;
        if (grow < n) {
            float sc = dinv[grow];
#pragma unroll
            for (int c = 0; c < 8; c++)
                H[(size_t)grow * 128 + c * 16 + l16] = f2bf(sc * acc[c][r]);
        }
    }
}

// ---------------- aggregation ----------------
// H rows pre-scaled by dinv (in gemm epilogue), so:
// out[n] = dinv[n] * ( sum_e w * H'[src] + H'[n] ) + b      (opt ReLU)
// Work-stealing: 16 groups of 16 lanes pop nodes off an LDS cursor; simple 4-wide
// batches (VGPR ~36 -> full TLP; deeper ILP measured twice as a net loss).
// BW pinned at ~3.5 TB/s across occ 36-69% -> random-gather service ceiling. FROZEN.
#define NODES_PER_BLK 16

__device__ __forceinline__ void acc8(float wt, uint4 hv, float* a) {
    a[0] += wt * bflo(hv.x); a[1] += wt * bfhi(hv.x);
    a[2] += wt * bflo(hv.y); a[3] += wt * bfhi(hv.y);
    a[4] += wt * bflo(hv.z); a[5] += wt * bfhi(hv.z);
    a[6] += wt * bflo(hv.w); a[7] += wt * bfhi(hv.w);
}

template <bool RELU, bool FINAL>
__global__ void k_aggregate(const unsigned short* __restrict__ H, const int* __restrict__ rowptr,
                            const uint2* __restrict__ csr, const float* __restrict__ dinv,
                            const void* __restrict__ bias, void* __restrict__ out,
                            const int* __restrict__ flags, int n) {
    __shared__ int cursor;
    if (threadIdx.x == 0) cursor = 0;
    __syncthreads();
    int lane = threadIdx.x & 15;
    int col = lane * 8;
    int f32m = flags[0];

    // bias hoisted: loaded once per thread, reused for every node
    float bv[8];
#pragma unroll
    for (int i = 0; i < 8; i++) bv[i] = load_f(bias, col + i, f32m);

    for (;;) {
        int idx;
        if (lane == 0) idx = atomicAdd(&cursor, 1);
        idx = __shfl(idx, 0, 16);
        if (idx >= NODES_PER_BLK) break;
        int node = blockIdx.x * NODES_PER_BLK + idx;
        if (node >= n) break;  // idx monotone per group -> all later pops also OOB

        int e0 = rowptr[node], e1 = rowptr[node + 1];
        uint4 u = *(const uint4*)(H + (size_t)node * 128 + col);  // self-row, early
        float dn = dinv[node];

        float a[8] = {0.f, 0.f, 0.f, 0.f, 0.f, 0.f, 0.f, 0.f};
        int e = e0;
        for (; e + 4 <= e1; e += 4) {
            uint2 c0 = csr[e], c1 = csr[e + 1], c2 = csr[e + 2], c3 = csr[e + 3];
            uint4 h0 = *(const uint4*)(H + (size_t)(c0.x & 0x1FFFF) * 128 + col);
            uint4 h1 = *(const uint4*)(H + (size_t)(c1.x & 0x1FFFF) * 128 + col);
            uint4 h2 = *(const uint4*)(H + (size_t)(c2.x & 0x1FFFF) * 128 + col);
            uint4 h3 = *(const uint4*)(H + (size_t)(c3.x & 0x1FFFF) * 128 + col);
            acc8(asf(c0.y), h0, a); acc8(asf(c1.y), h1, a);
            acc8(asf(c2.y), h2, a); acc8(asf(c3.y), h3, a);
        }
        for (; e < e1; e++) {
            uint2 c = csr[e];
            uint4 hh = *(const uint4*)(H + (size_t)(c.x & 0x1FFFF) * 128 + col);
            acc8(asf(c.y), hh, a);
        }

        a[0] = dn * (a[0] + bflo(u.x)) + bv[0];
        a[1] = dn * (a[1] + bfhi(u.x)) + bv[1];
        a[2] = dn * (a[2] + bflo(u.y)) + bv[2];
        a[3] = dn * (a[3] + bfhi(u.y)) + bv[3];
        a[4] = dn * (a[4] + bflo(u.z)) + bv[4];
        a[5] = dn * (a[5] + bfhi(u.z)) + bv[5];
        a[6] = dn * (a[6] + bflo(u.w)) + bv[6];
        a[7] = dn * (a[7] + bfhi(u.w)) + bv[7];

        if (RELU) {
#pragma unroll
            for (int i = 0; i < 8; i++) a[i] = fmaxf(a[i], 0.f);
        }
        if (FINAL && f32m) {
            float* op = (float*)out + (size_t)node * 128 + col;
            float4 o0 = {a[0], a[1], a[2], a[3]};
            float4 o1 = {a[4], a[5], a[6], a[7]};
            *(float4*)op = o0;
            *(float4*)(op + 4) = o1;
        } else {
            uint4 o;
            o.x = pack2(a[0], a[1]); o.y = pack2(a[2], a[3]);
            o.z = pack2(a[4], a[5]); o.w = pack2(a[6], a[7]);
            *(uint4*)((unsigned short*)out + (size_t)node * 128 + col) = o;
        }
    }
}

extern "C" void kernel_launch(void* const* d_in, const int* in_sizes, int n_in,
                              void* d_out, int out_size, void* d_ws, size_t ws_size,
                              hipStream_t stream) {
    const void* x  = d_in[0];
    const void* ei = d_in[1];
    const void* ew = d_in[2];
    const void* W1 = d_in[3];
    const void* b1 = d_in[4];
    const void* W2 = d_in[5];
    const void* b2 = d_in[6];

    char* p = (char*)d_ws;
    auto alloc = [&](size_t bytes) { char* r = p; p += (bytes + 255) & ~(size_t)255; return r; };
    int*   flags    = (int*)alloc(256);
    float* dinv     = (float*)alloc((size_t)N_NODES * 4);
    int*   rowptr   = (int*)alloc((size_t)(N_NODES + 1) * 4);
    int*   bucket_cursor = (int*)alloc((size_t)NBUCK * 4);
    int*   bucket_base   = (int*)alloc((size_t)(NBUCK + 1) * 4);
    uint2* csr      = (uint2*)alloc((size_t)N_EDGES * 8);
    unsigned short* W1T  = (unsigned short*)alloc((size_t)IN_DIM * HID_DIM * 2);
    unsigned short* W2T  = (unsigned short*)alloc((size_t)HID_DIM * OUT_DIM * 2);
    unsigned short* hbuf = (unsigned short*)alloc((size_t)N_NODES * 128 * 2);
    unsigned short* zbuf = (unsigned short*)alloc((size_t)N_NODES * 128 * 2);
    uint2* ebuf = (uint2*)hbuf;  // padded bucket space: NBUCK*BCAP*8 = 14.8 MB < 25.6 MB

    int nbC = (N_EDGES + CHUNK - 1) / CHUNK;                  // 391
    int nbG = (N_NODES + 127) / 128;                          // 782
    int nbA = (N_NODES + NODES_PER_BLK - 1) / NODES_PER_BLK;  // 6250

    k_detect<<<1, 512, 0, stream>>>((const unsigned int*)x, (const unsigned int*)ei, flags, bucket_cursor);
    k_bscatter<<<nbC, 256, 0, stream>>>(ei, ew, flags, bucket_cursor, ebuf, N_EDGES);
    k_bscan<<<1, 512, 0, stream>>>(bucket_cursor, bucket_base, rowptr);
    k_fine<<<NBUCK, 512, 0, stream>>>(ebuf, bucket_base, csr, rowptr, dinv, N_NODES);
    k_transpose<<<(IN_DIM * HID_DIM + HID_DIM * OUT_DIM + 255) / 256, 256, 0, stream>>>(W1, W2, flags, W1T, W2T);

    k_gemm<IN_DIM, true><<<nbG, 512, 0, stream>>>(x, W1T, dinv, hbuf, flags, N_NODES);
    k_aggregate<true, false><<<nbA, 256, 0, stream>>>(hbuf, rowptr, csr, dinv,
                                                      b1, zbuf, flags, N_NODES);
    k_gemm<HID_DIM, false><<<nbG, 512, 0, stream>>>(zbuf, W2T, dinv, hbuf, flags, N_NODES);
    k_aggregate<false, true><<<nbA, 256, 0, stream>>>(hbuf, rowptr, csr, dinv,
                                                      b2, d_out, flags, N_NODES);
}